// Round 4
// baseline (1551.870 us; speedup 1.0000x reference)
//
#include <hip/hip_runtime.h>
#include <cstdint>

// NOTE: all float tensors are FP32 per the reference (jnp.float32); output fp32.
// Intermediates stored bf16 (as u16) for footprint/BW; all accumulation fp32.

typedef unsigned short u16;
typedef u16 u16x8 __attribute__((ext_vector_type(8)));
typedef float f4 __attribute__((ext_vector_type(4)));

#define EPS 1e-5f
#define BB 2
#define CIN 64
#define CH 32
#define SVOX 64000
#define NC 100000
#define NF 400000

static __device__ __forceinline__ float b2f(u16 h) {
    return __builtin_bit_cast(float, (unsigned)h << 16);
}
static __device__ __forceinline__ u16 f2b(float f) {
    unsigned u = __builtin_bit_cast(unsigned, f);
    u += 0x7FFFu + ((u >> 16) & 1u);
    return (u16)(u >> 16);
}

// ---------------- zero stats accumulators ----------------
__global__ __launch_bounds__(256) void k_zero(float* __restrict__ p, int n) {
    int i = blockIdx.x * 256 + threadIdx.x;
    if (i < n) p[i] = 0.f;
}

// ---------------- transpose x2 f32 [B][32][Nf] -> x2t bf16 [B][Nf][32] ----------
__global__ __launch_bounds__(256) void k_x2t(
    const float* __restrict__ x2, u16* __restrict__ x2t)
{
    __shared__ u16 tile[64][40];
    int tid = threadIdx.x, b = blockIdx.y;
    int n0 = blockIdx.x * 64;
    int c = tid >> 3, no = (tid & 7) * 8;
    const float* src = x2 + ((size_t)b * CH + c) * NF + n0 + no;
    f4 v0 = *(const f4*)src;
    f4 v1 = *(const f4*)(src + 4);
#pragma unroll
    for (int i = 0; i < 4; i++) tile[no + i][c] = f2b(v0[i]);
#pragma unroll
    for (int i = 0; i < 4; i++) tile[no + 4 + i][c] = f2b(v1[i]);
    __syncthreads();
    int n = tid >> 2, co = (tid & 3) * 8;
    u16x8 ov;
#pragma unroll
    for (int i = 0; i < 8; i++) ov[i] = tile[n][co + i];
    *(u16x8*)(x2t + ((size_t)b * NF + n0 + n) * CH + co) = ov;
}

// ---------------- stage A: dense 1x1x1 conv (64 -> 32), y bf16 voxel-major ------
__global__ __launch_bounds__(256) void k_reduce(
    const float* __restrict__ x1, const float* __restrict__ wr,
    u16* __restrict__ y)
{
    __shared__ float wl[CIN * CH];
    int tid = threadIdx.x, b = blockIdx.y;
    for (int i = tid; i < CIN * CH; i += 256) {
        int c = i >> 5, o = i & 31;
        wl[i] = wr[o * CIN + c];   // wl[c][o]
    }
    __syncthreads();
    int s0 = blockIdx.x * 512 + tid;
    int s1 = s0 + 256;
    const float* xb = x1 + (size_t)b * CIN * SVOX;
    float acc0[CH], acc1[CH];
#pragma unroll
    for (int o = 0; o < CH; o++) { acc0[o] = 0.f; acc1[o] = 0.f; }
    for (int c = 0; c < CIN; c++) {
        float xv0 = xb[(size_t)c * SVOX + s0];
        float xv1 = xb[(size_t)c * SVOX + s1];
        const float* w = &wl[c * CH];
#pragma unroll
        for (int o = 0; o < CH; o++) {
            float wv = w[o];
            acc0[o] = fmaf(xv0, wv, acc0[o]);
            acc1[o] = fmaf(xv1, wv, acc1[o]);
        }
    }
    u16* y0 = y + ((size_t)b * SVOX + s0) * CH;
    u16* y1 = y + ((size_t)b * SVOX + s1) * CH;
#pragma unroll
    for (int g = 0; g < 4; g++) {
        u16x8 v0, v1;
#pragma unroll
        for (int i = 0; i < 8; i++) {
            v0[i] = f2b(acc0[g * 8 + i]);
            v1[i] = f2b(acc1[g * 8 + i]);
        }
        ((u16x8*)y0)[g] = v0;
        ((u16x8*)y1)[g] = v1;
    }
}

// ---------------- per-channel stats over rows, bf16 input [B][rows][32] ----------
__global__ __launch_bounds__(256) void k_statsB(
    const u16* __restrict__ x, float* __restrict__ stats, int rows)
{
    __shared__ float sred[CH * 2];
    int tid = threadIdx.x, b = blockIdx.y;
    if (tid < CH * 2) sred[tid] = 0.f;
    __syncthreads();
    int o = tid & 31, stripe = tid >> 5;
    const u16* xb = x + (size_t)b * rows * CH;
    int r0 = blockIdx.x * 512 + stripe * 64;
    float s = 0.f, q = 0.f;
    for (int i = 0; i < 64; i++) {
        int r = r0 + i;
        if (r < rows) {
            float v = b2f(xb[(size_t)r * CH + o]);
            s += v; q = fmaf(v, v, q);
        }
    }
    atomicAdd(&sred[o * 2], s);
    atomicAdd(&sred[o * 2 + 1], q);
    __syncthreads();
    if (tid < CH * 2) atomicAdd(&stats[(size_t)(b * CH * 2 + tid) * 32], sred[tid]);
}

// ---------------- per-channel stats over rows, f32 input [B][rows][32] ----------
__global__ __launch_bounds__(256) void k_statsF(
    const float* __restrict__ x, float* __restrict__ stats, int rows)
{
    __shared__ float sred[CH * 2];
    int tid = threadIdx.x, b = blockIdx.y;
    if (tid < CH * 2) sred[tid] = 0.f;
    __syncthreads();
    int o = tid & 31, stripe = tid >> 5;
    const float* xb = x + (size_t)b * rows * CH;
    int r0 = blockIdx.x * 512 + stripe * 64;
    float s = 0.f, q = 0.f;
    for (int i = 0; i < 64; i++) {
        int r = r0 + i;
        if (r < rows) {
            float v = xb[(size_t)r * CH + o];
            s += v; q = fmaf(v, v, q);
        }
    }
    atomicAdd(&sred[o * 2], s);
    atomicAdd(&sred[o * 2 + 1], q);
    __syncthreads();
    if (tid < CH * 2) atomicAdd(&stats[(size_t)(b * CH * 2 + tid) * 32], sred[tid]);
}

// ---------------- finalize stats -> per-channel scale/shift (gamma/beta f32) -----
__global__ void k_fin(const float* __restrict__ stats, const float* __restrict__ gamma,
                      const float* __restrict__ beta, float* __restrict__ ss, float invN)
{
    int i = threadIdx.x;
    if (i >= BB * CH) return;
    float sum = stats[(size_t)(i * 2) * 32];
    float sq  = stats[(size_t)(i * 2 + 1) * 32];
    float mean = sum * invN;
    float var = sq * invN - mean * mean;
    float rstd = rsqrtf(var + EPS);
    int o = i & 31;
    float sc = rstd * gamma[o];
    ss[i * 2] = sc;
    ss[i * 2 + 1] = beta[o] - mean * sc;
}

// ---------------- normalized coarse table [B][Nc][32] bf16 ----------------
__global__ __launch_bounds__(256) void k_coarse(
    const u16* __restrict__ y, const float* __restrict__ ssA,
    const int* __restrict__ sidx, u16* __restrict__ coarseN)
{
    __shared__ float sl[CH * 2];
    int tid = threadIdx.x, b = blockIdx.y;
    if (tid < CH * 2) sl[tid] = ssA[b * CH * 2 + tid];
    __syncthreads();
    int u = blockIdx.x * 256 + tid;
    if (u >= NC) return;
    int j = sidx[(size_t)b * NC + u];
    const u16x8* yr = (const u16x8*)(y + ((size_t)b * SVOX + j) * CH);
    u16x8* out = (u16x8*)(coarseN + ((size_t)b * NC + u) * CH);
#pragma unroll
    for (int g = 0; g < 4; g++) {
        u16x8 v = yr[g];
        u16x8 ov;
#pragma unroll
        for (int i = 0; i < 8; i++) {
            int c = g * 8 + i;
            ov[i] = f2b(fmaxf(fmaf(b2f(v[i]), sl[c * 2], sl[c * 2 + 1]), 0.f));
        }
        out[g] = ov;
    }
}

// ---------------- conv1: VALU gather-conv, Cin=64 -> h1 f32 in d_out -------------
// Each thread: 2 particles, 32 fp32 accumulators each. Weights in LDS fp32.
__global__ __launch_bounds__(256) void k_conv1(
    const u16* __restrict__ x2t, const u16* __restrict__ coarseN,
    const float* __restrict__ w1, const int* __restrict__ uidx,
    const int* __restrict__ nbr, float* __restrict__ h1)
{
    __shared__ float wl[7 * CIN * CH];   // wl[(k*64+c)*32 + o] = w1[o][c][k]
    int tid = threadIdx.x, b = blockIdx.y;
    for (int i = tid; i < 7 * CIN * CH; i += 256) {
        int o = i & 31, c = (i >> 5) & 63, k = i >> 11;
        wl[i] = w1[(o * CIN + c) * 7 + k];
    }
    __syncthreads();
    int n0 = blockIdx.x * 512 + tid;
    int n1 = n0 + 256;
    bool a0 = n0 < NF, a1 = n1 < NF;
    const u16* Xlo = x2t + (size_t)b * NF * CH;
    const u16* Xhi = coarseN + (size_t)b * NC * CH;
    const int* nbb = nbr + (size_t)b * NF * 7;
    const int* ub = uidx + (size_t)b * NF;
    float acc0[CH], acc1[CH];
#pragma unroll
    for (int o = 0; o < CH; o++) { acc0[o] = 0.f; acc1[o] = 0.f; }
    for (int k = 0; k < 7; k++) {
        int i0 = a0 ? nbb[(size_t)n0 * 7 + k] : 0;
        int i1 = a1 ? nbb[(size_t)n1 * 7 + k] : 0;
        int c0 = ub[i0], c1 = ub[i1];
        const u16x8* lo0 = (const u16x8*)(Xlo + (size_t)i0 * CH);
        const u16x8* lo1 = (const u16x8*)(Xlo + (size_t)i1 * CH);
        const u16x8* hi0 = (const u16x8*)(Xhi + (size_t)c0 * CH);
        const u16x8* hi1 = (const u16x8*)(Xhi + (size_t)c1 * CH);
        const float* wk = &wl[k * CIN * CH];
        // low half: channels 0..31 (x2), high half: 32..63 (fine/coarse)
        for (int cg = 0; cg < 4; cg++) {
            u16x8 v0 = lo0[cg], v1 = lo1[cg];
#pragma unroll
            for (int j = 0; j < 8; j++) {
                float xv0 = b2f(v0[j]), xv1 = b2f(v1[j]);
                const f4* w4 = (const f4*)(wk + (cg * 8 + j) * CH);
#pragma unroll
                for (int og = 0; og < 8; og++) {
                    f4 w = w4[og];
#pragma unroll
                    for (int u = 0; u < 4; u++) {
                        acc0[og * 4 + u] = fmaf(xv0, w[u], acc0[og * 4 + u]);
                        acc1[og * 4 + u] = fmaf(xv1, w[u], acc1[og * 4 + u]);
                    }
                }
            }
        }
        for (int cg = 0; cg < 4; cg++) {
            u16x8 v0 = hi0[cg], v1 = hi1[cg];
#pragma unroll
            for (int j = 0; j < 8; j++) {
                float xv0 = b2f(v0[j]), xv1 = b2f(v1[j]);
                const f4* w4 = (const f4*)(wk + (32 + cg * 8 + j) * CH);
#pragma unroll
                for (int og = 0; og < 8; og++) {
                    f4 w = w4[og];
#pragma unroll
                    for (int u = 0; u < 4; u++) {
                        acc0[og * 4 + u] = fmaf(xv0, w[u], acc0[og * 4 + u]);
                        acc1[og * 4 + u] = fmaf(xv1, w[u], acc1[og * 4 + u]);
                    }
                }
            }
        }
    }
    if (a0) {
        f4* out = (f4*)(h1 + ((size_t)b * NF + n0) * CH);
#pragma unroll
        for (int og = 0; og < 8; og++) {
            f4 t;
#pragma unroll
            for (int u = 0; u < 4; u++) t[u] = acc0[og * 4 + u];
            out[og] = t;
        }
    }
    if (a1) {
        f4* out = (f4*)(h1 + ((size_t)b * NF + n1) * CH);
#pragma unroll
        for (int og = 0; og < 8; og++) {
            f4 t;
#pragma unroll
            for (int u = 0; u < 4; u++) t[u] = acc1[og * 4 + u];
            out[og] = t;
        }
    }
}

// ---------------- normalize+relu h1 f32 in place (on d_out) ----------------
__global__ __launch_bounds__(256) void k_norm1(
    float* __restrict__ h, const float* __restrict__ ss)
{
    __shared__ float sl[BB * CH * 2];
    int tid = threadIdx.x;
    if (tid < BB * CH * 2) sl[tid] = ss[tid];
    __syncthreads();
    size_t f = ((size_t)blockIdx.x * 256 + tid) * 8;
    int b = (int)(f / ((size_t)NF * CH));
    int c0 = (int)(f & (CH - 1));
    f4 v0 = *(const f4*)(h + f);
    f4 v1 = *(const f4*)(h + f + 4);
#pragma unroll
    for (int i = 0; i < 4; i++) {
        int c = c0 + i;
        v0[i] = fmaxf(fmaf(v0[i], sl[(b * CH + c) * 2], sl[(b * CH + c) * 2 + 1]), 0.f);
    }
#pragma unroll
    for (int i = 0; i < 4; i++) {
        int c = c0 + 4 + i;
        v1[i] = fmaxf(fmaf(v1[i], sl[(b * CH + c) * 2], sl[(b * CH + c) * 2 + 1]), 0.f);
    }
    *(f4*)(h + f) = v0;
    *(f4*)(h + f + 4) = v1;
}

// ---------------- conv2: VALU gather-conv, Cin=32, f32 in -> h2 bf16 -------------
__global__ __launch_bounds__(256) void k_conv2(
    const float* __restrict__ x, const float* __restrict__ w2,
    const int* __restrict__ nbr, u16* __restrict__ h2)
{
    __shared__ float wl[7 * CH * CH];    // wl[(k*32+c)*32 + o] = w2[o][c][k]
    int tid = threadIdx.x, b = blockIdx.y;
    for (int i = tid; i < 7 * CH * CH; i += 256) {
        int o = i & 31, c = (i >> 5) & 31, k = i >> 10;
        wl[i] = w2[(o * CH + c) * 7 + k];
    }
    __syncthreads();
    int n0 = blockIdx.x * 512 + tid;
    int n1 = n0 + 256;
    bool a0 = n0 < NF, a1 = n1 < NF;
    const float* Xb = x + (size_t)b * NF * CH;
    const int* nbb = nbr + (size_t)b * NF * 7;
    float acc0[CH], acc1[CH];
#pragma unroll
    for (int o = 0; o < CH; o++) { acc0[o] = 0.f; acc1[o] = 0.f; }
    for (int k = 0; k < 7; k++) {
        int i0 = a0 ? nbb[(size_t)n0 * 7 + k] : 0;
        int i1 = a1 ? nbb[(size_t)n1 * 7 + k] : 0;
        const f4* r0 = (const f4*)(Xb + (size_t)i0 * CH);
        const f4* r1 = (const f4*)(Xb + (size_t)i1 * CH);
        const float* wk = &wl[k * CH * CH];
        for (int cg = 0; cg < 8; cg++) {
            f4 v0 = r0[cg], v1 = r1[cg];
#pragma unroll
            for (int j = 0; j < 4; j++) {
                float xv0 = v0[j], xv1 = v1[j];
                const f4* w4 = (const f4*)(wk + (cg * 4 + j) * CH);
#pragma unroll
                for (int og = 0; og < 8; og++) {
                    f4 w = w4[og];
#pragma unroll
                    for (int u = 0; u < 4; u++) {
                        acc0[og * 4 + u] = fmaf(xv0, w[u], acc0[og * 4 + u]);
                        acc1[og * 4 + u] = fmaf(xv1, w[u], acc1[og * 4 + u]);
                    }
                }
            }
        }
    }
    if (a0) {
        u16x8* out = (u16x8*)(h2 + ((size_t)b * NF + n0) * CH);
#pragma unroll
        for (int g = 0; g < 4; g++) {
            u16x8 t;
#pragma unroll
            for (int i = 0; i < 8; i++) t[i] = f2b(acc0[g * 8 + i]);
            out[g] = t;
        }
    }
    if (a1) {
        u16x8* out = (u16x8*)(h2 + ((size_t)b * NF + n1) * CH);
#pragma unroll
        for (int g = 0; g < 4; g++) {
            u16x8 t;
#pragma unroll
            for (int i = 0; i < 8; i++) t[i] = f2b(acc1[g * 8 + i]);
            out[g] = t;
        }
    }
}

// ---------------- normalize+relu+transpose -> d_out f32 [B][32][Nf] --------------
__global__ __launch_bounds__(256) void k_norm2(
    const u16* __restrict__ h, const float* __restrict__ ss, float* __restrict__ out)
{
    __shared__ float sl[CH * 2];
    __shared__ float tile[CH][72];
    int tid = threadIdx.x, b = blockIdx.y;
    if (tid < CH * 2) sl[tid] = ss[b * CH * 2 + tid];
    __syncthreads();
    int n0 = blockIdx.x * 64;
    int p = tid >> 2, c0 = (tid & 3) * 8;
    u16x8 v = *(const u16x8*)(h + ((size_t)b * NF + n0 + p) * CH + c0);
#pragma unroll
    for (int i = 0; i < 8; i++) {
        int c = c0 + i;
        tile[c][p] = fmaxf(fmaf(b2f(v[i]), sl[c * 2], sl[c * 2 + 1]), 0.f);
    }
    __syncthreads();
    int c = tid >> 3, p0 = (tid & 7) * 8;
    f4 o0, o1;
#pragma unroll
    for (int i = 0; i < 4; i++) { o0[i] = tile[c][p0 + i]; o1[i] = tile[c][p0 + 4 + i]; }
    float* dst = out + ((size_t)b * CH + c) * NF + n0 + p0;
    *(f4*)dst = o0;
    *(f4*)(dst + 4) = o1;
}

extern "C" void kernel_launch(void* const* d_in, const int* in_sizes, int n_in,
                              void* d_out, int out_size, void* d_ws, size_t ws_size,
                              hipStream_t stream)
{
    const float* x1 = (const float*)d_in[0];
    const float* x2 = (const float*)d_in[1];
    const float* wr = (const float*)d_in[2];
    const float* gA = (const float*)d_in[3];
    const float* bA = (const float*)d_in[4];
    const float* w1 = (const float*)d_in[5];
    const float* g1 = (const float*)d_in[6];
    const float* b1 = (const float*)d_in[7];
    const float* w2 = (const float*)d_in[8];
    const float* g2 = (const float*)d_in[9];
    const float* b2 = (const float*)d_in[10];
    const int* sidx = (const int*)d_in[11];
    const int* uidx = (const int*)d_in[12];
    const int* nbr  = (const int*)d_in[13];

    // ws (~72.3 MB): x2t bf16 51.2MB | y bf16 8.19MB | coarseN bf16 12.8MB | stats tail.
    // h1 f32 [B][Nf][32] = 102.4MB lives exactly in d_out; h2 bf16 aliases dead x2t.
    char* ws = (char*)d_ws;
    u16* x2t     = (u16*)ws;
    u16* h2      = (u16*)ws;                            // alias: x2t dead after conv1
    u16* y       = (u16*)(ws + 51200000);
    u16* coarseN = (u16*)(ws + 59392000);
    float* statsA = (float*)(ws + 72192000);            // 3 x 16 KB padded accumulators
    float* stats1 = (float*)(ws + 72192000 + 16384);
    float* stats2 = (float*)(ws + 72192000 + 32768);
    float* ssA    = (float*)(ws + 72192000 + 49152);    // 3 x 512 B scale/shift tables
    float* ss1    = (float*)(ws + 72192000 + 49664);
    float* ss2    = (float*)(ws + 72192000 + 50176);
    float* h1 = (float*)d_out;                          // d_out as [B][Nf][32] f32 scratch

    k_zero<<<48, 256, 0, stream>>>(statsA, 12288);
    k_x2t<<<dim3(6250, BB), 256, 0, stream>>>(x2, x2t);
    k_reduce<<<dim3(125, BB), 256, 0, stream>>>(x1, wr, y);
    k_statsB<<<dim3(125, BB), 256, 0, stream>>>(y, statsA, SVOX);
    k_fin<<<1, 64, 0, stream>>>(statsA, gA, bA, ssA, 1.f / SVOX);
    k_coarse<<<dim3(391, BB), 256, 0, stream>>>(y, ssA, sidx, coarseN);
    k_conv1<<<dim3(782, BB), 256, 0, stream>>>(x2t, coarseN, w1, uidx, nbr, h1);
    k_statsF<<<dim3(782, BB), 256, 0, stream>>>(h1, stats1, NF);
    k_fin<<<1, 64, 0, stream>>>(stats1, g1, b1, ss1, 1.f / NF);
    k_norm1<<<12500, 256, 0, stream>>>(h1, ss1);
    k_conv2<<<dim3(782, BB), 256, 0, stream>>>(h1, w2, nbr, h2);
    k_statsB<<<dim3(782, BB), 256, 0, stream>>>(h2, stats2, NF);
    k_fin<<<1, 64, 0, stream>>>(stats2, g2, b2, ss2, 1.f / NF);
    k_norm2<<<dim3(6250, BB), 256, 0, stream>>>(h2, ss2, (float*)d_out);
}

// Round 5
// 1215.442 us; speedup vs baseline: 1.2768x; 1.2768x over previous
//
#include <hip/hip_runtime.h>
#include <cstdint>

// FP32 external interface (reference is jnp.float32). Intermediates bf16 (u16),
// all accumulation fp32. Key change R5: h1 stored as bf16 64-B records so
// conv2's random gather moves half the bytes (conv2 was fetch-byte-bound:
// 2.06 GB @ 3.2 TB/s == its 635 us duration).

typedef unsigned short u16;
typedef u16 u16x8 __attribute__((ext_vector_type(8)));
typedef float f4 __attribute__((ext_vector_type(4)));

#define EPS 1e-5f
#define BB 2
#define CIN 64
#define CH 32
#define SVOX 64000
#define NC 100000
#define NF 400000

static __device__ __forceinline__ float b2f(u16 h) {
    return __builtin_bit_cast(float, (unsigned)h << 16);
}
static __device__ __forceinline__ u16 f2b(float f) {
    unsigned u = __builtin_bit_cast(unsigned, f);
    u += 0x7FFFu + ((u >> 16) & 1u);
    return (u16)(u >> 16);
}

// ---------------- zero stats accumulators ----------------
__global__ __launch_bounds__(256) void k_zero(float* __restrict__ p, int n) {
    int i = blockIdx.x * 256 + threadIdx.x;
    if (i < n) p[i] = 0.f;
}

// ---------------- transpose x2 f32 [B][32][Nf] -> x2t bf16 [B][Nf][32] ----------
__global__ __launch_bounds__(256) void k_x2t(
    const float* __restrict__ x2, u16* __restrict__ x2t)
{
    __shared__ u16 tile[64][40];
    int tid = threadIdx.x, b = blockIdx.y;
    int n0 = blockIdx.x * 64;
    int c = tid >> 3, no = (tid & 7) * 8;
    const float* src = x2 + ((size_t)b * CH + c) * NF + n0 + no;
    f4 v0 = *(const f4*)src;
    f4 v1 = *(const f4*)(src + 4);
#pragma unroll
    for (int i = 0; i < 4; i++) tile[no + i][c] = f2b(v0[i]);
#pragma unroll
    for (int i = 0; i < 4; i++) tile[no + 4 + i][c] = f2b(v1[i]);
    __syncthreads();
    int n = tid >> 2, co = (tid & 3) * 8;
    u16x8 ov;
#pragma unroll
    for (int i = 0; i < 8; i++) ov[i] = tile[n][co + i];
    *(u16x8*)(x2t + ((size_t)b * NF + n0 + n) * CH + co) = ov;
}

// ---------------- stage A: dense 1x1x1 conv (64 -> 32), y bf16 voxel-major ------
__global__ __launch_bounds__(256) void k_reduce(
    const float* __restrict__ x1, const float* __restrict__ wr,
    u16* __restrict__ y)
{
    __shared__ float wl[CIN * CH];
    int tid = threadIdx.x, b = blockIdx.y;
    for (int i = tid; i < CIN * CH; i += 256) {
        int c = i >> 5, o = i & 31;
        wl[i] = wr[o * CIN + c];   // wl[c][o]
    }
    __syncthreads();
    int s0 = blockIdx.x * 512 + tid;
    int s1 = s0 + 256;
    const float* xb = x1 + (size_t)b * CIN * SVOX;
    float acc0[CH], acc1[CH];
#pragma unroll
    for (int o = 0; o < CH; o++) { acc0[o] = 0.f; acc1[o] = 0.f; }
    for (int c = 0; c < CIN; c++) {
        float xv0 = xb[(size_t)c * SVOX + s0];
        float xv1 = xb[(size_t)c * SVOX + s1];
        const float* w = &wl[c * CH];
#pragma unroll
        for (int o = 0; o < CH; o++) {
            float wv = w[o];
            acc0[o] = fmaf(xv0, wv, acc0[o]);
            acc1[o] = fmaf(xv1, wv, acc1[o]);
        }
    }
    u16* y0 = y + ((size_t)b * SVOX + s0) * CH;
    u16* y1 = y + ((size_t)b * SVOX + s1) * CH;
#pragma unroll
    for (int g = 0; g < 4; g++) {
        u16x8 v0, v1;
#pragma unroll
        for (int i = 0; i < 8; i++) {
            v0[i] = f2b(acc0[g * 8 + i]);
            v1[i] = f2b(acc1[g * 8 + i]);
        }
        ((u16x8*)y0)[g] = v0;
        ((u16x8*)y1)[g] = v1;
    }
}

// ---------------- per-channel stats over rows, bf16 input [B][rows][32] ----------
__global__ __launch_bounds__(256) void k_statsB(
    const u16* __restrict__ x, float* __restrict__ stats, int rows)
{
    __shared__ float sred[CH * 2];
    int tid = threadIdx.x, b = blockIdx.y;
    if (tid < CH * 2) sred[tid] = 0.f;
    __syncthreads();
    int o = tid & 31, stripe = tid >> 5;
    const u16* xb = x + (size_t)b * rows * CH;
    int r0 = blockIdx.x * 512 + stripe * 64;
    float s = 0.f, q = 0.f;
    for (int i = 0; i < 64; i++) {
        int r = r0 + i;
        if (r < rows) {
            float v = b2f(xb[(size_t)r * CH + o]);
            s += v; q = fmaf(v, v, q);
        }
    }
    atomicAdd(&sred[o * 2], s);
    atomicAdd(&sred[o * 2 + 1], q);
    __syncthreads();
    if (tid < CH * 2) atomicAdd(&stats[(size_t)(b * CH * 2 + tid) * 32], sred[tid]);
}

// ---------------- finalize stats -> per-channel scale/shift ----------------
__global__ void k_fin(const float* __restrict__ stats, const float* __restrict__ gamma,
                      const float* __restrict__ beta, float* __restrict__ ss, float invN)
{
    int i = threadIdx.x;
    if (i >= BB * CH) return;
    float sum = stats[(size_t)(i * 2) * 32];
    float sq  = stats[(size_t)(i * 2 + 1) * 32];
    float mean = sum * invN;
    float var = sq * invN - mean * mean;
    float rstd = rsqrtf(var + EPS);
    int o = i & 31;
    float sc = rstd * gamma[o];
    ss[i * 2] = sc;
    ss[i * 2 + 1] = beta[o] - mean * sc;
}

// ---------------- normalized coarse table [B][Nc][32] bf16 ----------------
__global__ __launch_bounds__(256) void k_coarse(
    const u16* __restrict__ y, const float* __restrict__ ssA,
    const int* __restrict__ sidx, u16* __restrict__ coarseN)
{
    __shared__ float sl[CH * 2];
    int tid = threadIdx.x, b = blockIdx.y;
    if (tid < CH * 2) sl[tid] = ssA[b * CH * 2 + tid];
    __syncthreads();
    int u = blockIdx.x * 256 + tid;
    if (u >= NC) return;
    int j = sidx[(size_t)b * NC + u];
    const u16x8* yr = (const u16x8*)(y + ((size_t)b * SVOX + j) * CH);
    u16x8* out = (u16x8*)(coarseN + ((size_t)b * NC + u) * CH);
#pragma unroll
    for (int g = 0; g < 4; g++) {
        u16x8 v = yr[g];
        u16x8 ov;
#pragma unroll
        for (int i = 0; i < 8; i++) {
            int c = g * 8 + i;
            ov[i] = f2b(fmaxf(fmaf(b2f(v[i]), sl[c * 2], sl[c * 2 + 1]), 0.f));
        }
        out[g] = ov;
    }
}

// ---------------- conv1: VALU gather-conv, Cin=64 -> h1 bf16 in d_out ------------
__global__ __launch_bounds__(256) void k_conv1(
    const u16* __restrict__ x2t, const u16* __restrict__ coarseN,
    const float* __restrict__ w1, const int* __restrict__ uidx,
    const int* __restrict__ nbr, u16* __restrict__ h1)
{
    __shared__ float wl[7 * CIN * CH];   // wl[(k*64+c)*32 + o] = w1[o][c][k]
    int tid = threadIdx.x, b = blockIdx.y;
    for (int i = tid; i < 7 * CIN * CH; i += 256) {
        int o = i & 31, c = (i >> 5) & 63, k = i >> 11;
        wl[i] = w1[(o * CIN + c) * 7 + k];
    }
    __syncthreads();
    int n0 = blockIdx.x * 512 + tid;
    int n1 = n0 + 256;
    bool a0 = n0 < NF, a1 = n1 < NF;
    const u16* Xlo = x2t + (size_t)b * NF * CH;
    const u16* Xhi = coarseN + (size_t)b * NC * CH;
    const int* nbb = nbr + (size_t)b * NF * 7;
    const int* ub = uidx + (size_t)b * NF;
    float acc0[CH], acc1[CH];
#pragma unroll
    for (int o = 0; o < CH; o++) { acc0[o] = 0.f; acc1[o] = 0.f; }
    for (int k = 0; k < 7; k++) {
        int i0 = a0 ? nbb[(size_t)n0 * 7 + k] : 0;
        int i1 = a1 ? nbb[(size_t)n1 * 7 + k] : 0;
        int c0 = ub[i0], c1 = ub[i1];
        const u16x8* lo0 = (const u16x8*)(Xlo + (size_t)i0 * CH);
        const u16x8* lo1 = (const u16x8*)(Xlo + (size_t)i1 * CH);
        const u16x8* hi0 = (const u16x8*)(Xhi + (size_t)c0 * CH);
        const u16x8* hi1 = (const u16x8*)(Xhi + (size_t)c1 * CH);
        const float* wk = &wl[k * CIN * CH];
        for (int cg = 0; cg < 4; cg++) {
            u16x8 v0 = lo0[cg], v1 = lo1[cg];
#pragma unroll
            for (int j = 0; j < 8; j++) {
                float xv0 = b2f(v0[j]), xv1 = b2f(v1[j]);
                const f4* w4 = (const f4*)(wk + (cg * 8 + j) * CH);
#pragma unroll
                for (int og = 0; og < 8; og++) {
                    f4 w = w4[og];
#pragma unroll
                    for (int u = 0; u < 4; u++) {
                        acc0[og * 4 + u] = fmaf(xv0, w[u], acc0[og * 4 + u]);
                        acc1[og * 4 + u] = fmaf(xv1, w[u], acc1[og * 4 + u]);
                    }
                }
            }
        }
        for (int cg = 0; cg < 4; cg++) {
            u16x8 v0 = hi0[cg], v1 = hi1[cg];
#pragma unroll
            for (int j = 0; j < 8; j++) {
                float xv0 = b2f(v0[j]), xv1 = b2f(v1[j]);
                const f4* w4 = (const f4*)(wk + (32 + cg * 8 + j) * CH);
#pragma unroll
                for (int og = 0; og < 8; og++) {
                    f4 w = w4[og];
#pragma unroll
                    for (int u = 0; u < 4; u++) {
                        acc0[og * 4 + u] = fmaf(xv0, w[u], acc0[og * 4 + u]);
                        acc1[og * 4 + u] = fmaf(xv1, w[u], acc1[og * 4 + u]);
                    }
                }
            }
        }
    }
    if (a0) {
        u16x8* out = (u16x8*)(h1 + ((size_t)b * NF + n0) * CH);
#pragma unroll
        for (int g = 0; g < 4; g++) {
            u16x8 t;
#pragma unroll
            for (int i = 0; i < 8; i++) t[i] = f2b(acc0[g * 8 + i]);
            out[g] = t;
        }
    }
    if (a1) {
        u16x8* out = (u16x8*)(h1 + ((size_t)b * NF + n1) * CH);
#pragma unroll
        for (int g = 0; g < 4; g++) {
            u16x8 t;
#pragma unroll
            for (int i = 0; i < 8; i++) t[i] = f2b(acc1[g * 8 + i]);
            out[g] = t;
        }
    }
}

// ---------------- normalize+relu h1 bf16 in place (on d_out) ----------------
__global__ __launch_bounds__(256) void k_norm1b(
    u16* __restrict__ h, const float* __restrict__ ss)
{
    __shared__ float sl[BB * CH * 2];
    int tid = threadIdx.x;
    if (tid < BB * CH * 2) sl[tid] = ss[tid];
    __syncthreads();
    size_t f = ((size_t)blockIdx.x * 256 + tid) * 8;
    int b = (int)(f / ((size_t)NF * CH));
    int c0 = (int)(f & (CH - 1));
    u16x8 v = *(const u16x8*)(h + f);
    u16x8 ov;
#pragma unroll
    for (int i = 0; i < 8; i++) {
        int c = c0 + i;
        ov[i] = f2b(fmaxf(fmaf(b2f(v[i]), sl[(b * CH + c) * 2], sl[(b * CH + c) * 2 + 1]), 0.f));
    }
    *(u16x8*)(h + f) = ov;
}

// ---------------- conv2: VALU gather-conv, Cin=32, bf16 in -> h2 bf16 ------------
__global__ __launch_bounds__(256) void k_conv2(
    const u16* __restrict__ x, const float* __restrict__ w2,
    const int* __restrict__ nbr, u16* __restrict__ h2)
{
    __shared__ float wl[7 * CH * CH];    // wl[(k*32+c)*32 + o] = w2[o][c][k]
    int tid = threadIdx.x, b = blockIdx.y;
    for (int i = tid; i < 7 * CH * CH; i += 256) {
        int o = i & 31, c = (i >> 5) & 31, k = i >> 10;
        wl[i] = w2[(o * CH + c) * 7 + k];
    }
    __syncthreads();
    int n0 = blockIdx.x * 512 + tid;
    int n1 = n0 + 256;
    bool a0 = n0 < NF, a1 = n1 < NF;
    const u16* Xb = x + (size_t)b * NF * CH;
    const int* nbb = nbr + (size_t)b * NF * 7;
    float acc0[CH], acc1[CH];
#pragma unroll
    for (int o = 0; o < CH; o++) { acc0[o] = 0.f; acc1[o] = 0.f; }
    for (int k = 0; k < 7; k++) {
        int i0 = a0 ? nbb[(size_t)n0 * 7 + k] : 0;
        int i1 = a1 ? nbb[(size_t)n1 * 7 + k] : 0;
        const u16x8* r0 = (const u16x8*)(Xb + (size_t)i0 * CH);
        const u16x8* r1 = (const u16x8*)(Xb + (size_t)i1 * CH);
        const float* wk = &wl[k * CH * CH];
        for (int cg = 0; cg < 4; cg++) {
            u16x8 v0 = r0[cg], v1 = r1[cg];
#pragma unroll
            for (int j = 0; j < 8; j++) {
                float xv0 = b2f(v0[j]), xv1 = b2f(v1[j]);
                const f4* w4 = (const f4*)(wk + (cg * 8 + j) * CH);
#pragma unroll
                for (int og = 0; og < 8; og++) {
                    f4 w = w4[og];
#pragma unroll
                    for (int u = 0; u < 4; u++) {
                        acc0[og * 4 + u] = fmaf(xv0, w[u], acc0[og * 4 + u]);
                        acc1[og * 4 + u] = fmaf(xv1, w[u], acc1[og * 4 + u]);
                    }
                }
            }
        }
    }
    if (a0) {
        u16x8* out = (u16x8*)(h2 + ((size_t)b * NF + n0) * CH);
#pragma unroll
        for (int g = 0; g < 4; g++) {
            u16x8 t;
#pragma unroll
            for (int i = 0; i < 8; i++) t[i] = f2b(acc0[g * 8 + i]);
            out[g] = t;
        }
    }
    if (a1) {
        u16x8* out = (u16x8*)(h2 + ((size_t)b * NF + n1) * CH);
#pragma unroll
        for (int g = 0; g < 4; g++) {
            u16x8 t;
#pragma unroll
            for (int i = 0; i < 8; i++) t[i] = f2b(acc1[g * 8 + i]);
            out[g] = t;
        }
    }
}

// ---------------- normalize+relu+transpose -> d_out f32 [B][32][Nf] --------------
__global__ __launch_bounds__(256) void k_norm2(
    const u16* __restrict__ h, const float* __restrict__ ss, float* __restrict__ out)
{
    __shared__ float sl[CH * 2];
    __shared__ float tile[CH][72];
    int tid = threadIdx.x, b = blockIdx.y;
    if (tid < CH * 2) sl[tid] = ss[b * CH * 2 + tid];
    __syncthreads();
    int n0 = blockIdx.x * 64;
    int p = tid >> 2, c0 = (tid & 3) * 8;
    u16x8 v = *(const u16x8*)(h + ((size_t)b * NF + n0 + p) * CH + c0);
#pragma unroll
    for (int i = 0; i < 8; i++) {
        int c = c0 + i;
        tile[c][p] = fmaxf(fmaf(b2f(v[i]), sl[c * 2], sl[c * 2 + 1]), 0.f);
    }
    __syncthreads();
    int c = tid >> 3, p0 = (tid & 7) * 8;
    f4 o0, o1;
#pragma unroll
    for (int i = 0; i < 4; i++) { o0[i] = tile[c][p0 + i]; o1[i] = tile[c][p0 + 4 + i]; }
    float* dst = out + ((size_t)b * CH + c) * NF + n0 + p0;
    *(f4*)dst = o0;
    *(f4*)(dst + 4) = o1;
}

extern "C" void kernel_launch(void* const* d_in, const int* in_sizes, int n_in,
                              void* d_out, int out_size, void* d_ws, size_t ws_size,
                              hipStream_t stream)
{
    const float* x1 = (const float*)d_in[0];
    const float* x2 = (const float*)d_in[1];
    const float* wr = (const float*)d_in[2];
    const float* gA = (const float*)d_in[3];
    const float* bA = (const float*)d_in[4];
    const float* w1 = (const float*)d_in[5];
    const float* g1 = (const float*)d_in[6];
    const float* b1 = (const float*)d_in[7];
    const float* w2 = (const float*)d_in[8];
    const float* g2 = (const float*)d_in[9];
    const float* b2 = (const float*)d_in[10];
    const int* sidx = (const int*)d_in[11];
    const int* uidx = (const int*)d_in[12];
    const int* nbr  = (const int*)d_in[13];

    // ws (~72.3 MB): x2t bf16 51.2MB (h2 aliases it after conv1) | y bf16 8.19MB |
    // coarseN bf16 12.8MB | stats tail. h1 bf16 [B][Nf][32] = 51.2MB in d_out.
    char* ws = (char*)d_ws;
    u16* x2t     = (u16*)ws;
    u16* h2      = (u16*)ws;                            // alias: x2t dead after conv1
    u16* y       = (u16*)(ws + 51200000);
    u16* coarseN = (u16*)(ws + 59392000);
    float* statsA = (float*)(ws + 72192000);            // 3 x 16 KB padded accumulators
    float* stats1 = (float*)(ws + 72192000 + 16384);
    float* stats2 = (float*)(ws + 72192000 + 32768);
    float* ssA    = (float*)(ws + 72192000 + 49152);    // 3 x 512 B scale/shift tables
    float* ss1    = (float*)(ws + 72192000 + 49664);
    float* ss2    = (float*)(ws + 72192000 + 50176);
    u16* h1 = (u16*)d_out;                              // d_out lower half as bf16 scratch

    k_zero<<<48, 256, 0, stream>>>(statsA, 12288);
    k_x2t<<<dim3(6250, BB), 256, 0, stream>>>(x2, x2t);
    k_reduce<<<dim3(125, BB), 256, 0, stream>>>(x1, wr, y);
    k_statsB<<<dim3(125, BB), 256, 0, stream>>>(y, statsA, SVOX);
    k_fin<<<1, 64, 0, stream>>>(statsA, gA, bA, ssA, 1.f / SVOX);
    k_coarse<<<dim3(391, BB), 256, 0, stream>>>(y, ssA, sidx, coarseN);
    k_conv1<<<dim3(782, BB), 256, 0, stream>>>(x2t, coarseN, w1, uidx, nbr, h1);
    k_statsB<<<dim3(782, BB), 256, 0, stream>>>(h1, stats1, NF);
    k_fin<<<1, 64, 0, stream>>>(stats1, g1, b1, ss1, 1.f / NF);
    k_norm1b<<<12500, 256, 0, stream>>>(h1, ss1);
    k_conv2<<<dim3(782, BB), 256, 0, stream>>>(h1, w2, nbr, h2);
    k_statsB<<<dim3(782, BB), 256, 0, stream>>>(h2, stats2, NF);
    k_fin<<<1, 64, 0, stream>>>(stats2, g2, b2, ss2, 1.f / NF);
    k_norm2<<<dim3(6250, BB), 256, 0, stream>>>(h2, ss2, (float*)d_out);
}